// Round 4
// baseline (336.839 us; speedup 1.0000x reference)
//
#include <hip/hip_runtime.h>
#include <math.h>

#define B_  16
#define L_  2048
#define D_  512
#define K_  7
#define Q_  (B_*L_*D_)   // 16777216 elements per output tensor

// ---------------------------------------------------------------------------
// Kernel A: tiled transpose (B,L,D) -> (B,D,L) for q and k.
// ---------------------------------------------------------------------------
__global__ __launch_bounds__(256) void kA(const float* __restrict__ q,
                                          const float* __restrict__ k,
                                          float* __restrict__ qT,
                                          float* __restrict__ kT) {
  __shared__ float tq[32][33];
  __shared__ float tk[32][33];
  const int l0 = blockIdx.x * 32, d0 = blockIdx.y * 32, b = blockIdx.z;
  const int tx = threadIdx.x, ty = threadIdx.y;       // (32,8)
  const size_t ibase = (size_t)b * L_ * D_;
#pragma unroll
  for (int j = 0; j < 4; ++j) {
    const int l = l0 + ty + 8 * j;
    tq[ty + 8 * j][tx] = q[ibase + (size_t)l * D_ + d0 + tx];
    tk[ty + 8 * j][tx] = k[ibase + (size_t)l * D_ + d0 + tx];
  }
  __syncthreads();
  const size_t obase = (size_t)b * D_ * L_;
#pragma unroll
  for (int j = 0; j < 4; ++j) {
    const int d = d0 + ty + 8 * j;
    qT[obase + (size_t)d * L_ + l0 + tx] = tq[tx][ty + 8 * j];
    kT[obase + (size_t)d * L_ + l0 + tx] = tk[tx][ty + 8 * j];
  }
}

// ---------------------------------------------------------------------------
// Kernel B: 4 channels per block, 512 threads.
// Phase A: fwd FFT ch0 & ch1 CONCURRENTLY (one thread-half each), combine->U4.
// Phase B: fwd FFT ch2 & ch3 concurrently, combine->U2.
// Phase C: the two packed inverse FFTs run concurrently (U4<->U0, U2<->U1).
// Mixed-radix (8,8,8,4) Stockham, float2 complex LDS, XOR swizzle.
// ---------------------------------------------------------------------------
struct cf { float r, i; };
__device__ __forceinline__ cf cadd(cf a, cf b){ return {a.r+b.r, a.i+b.i}; }
__device__ __forceinline__ cf csub(cf a, cf b){ return {a.r-b.r, a.i-b.i}; }
__device__ __forceinline__ cf cmul(cf a, cf b){ return {a.r*b.r - a.i*b.i, a.r*b.i + a.i*b.r}; }
template<bool INV> __device__ __forceinline__ cf rot90(cf x){
  return INV ? cf{-x.i, x.r} : cf{x.i, -x.r};   // * +/- i
}
__device__ __forceinline__ int swz(int a){ return a ^ (((a >> 4) ^ (a >> 8)) & 15); }
__device__ __forceinline__ cf ldx(const float2* __restrict__ p, int i){
  const float2 v = p[swz(i)]; return {v.x, v.y};
}
__device__ __forceinline__ void stx(float2* __restrict__ p, int i, cf v){
  p[swz(i)] = {v.r, v.i};
}

template<bool INV>
__device__ __forceinline__ void dft8(cf a[8], cf b[8]) {
  const float H = 0.70710678118654752440f;
  cf t0 = cadd(a[0],a[4]), t1 = cadd(a[1],a[5]), t2 = cadd(a[2],a[6]), t3 = cadd(a[3],a[7]);
  cf u0 = csub(a[0],a[4]), u1 = csub(a[1],a[5]), u2 = csub(a[2],a[6]), u3 = csub(a[3],a[7]);
  const cf w1 = INV ? cf{H,  H} : cf{ H, -H};
  const cf w3 = INV ? cf{-H, H} : cf{-H, -H};
  u1 = cmul(u1, w1);
  u2 = rot90<INV>(u2);
  u3 = cmul(u3, w3);
  { cf s0 = cadd(t0,t2), s1 = csub(t0,t2), s2 = cadd(t1,t3), s3 = rot90<INV>(csub(t1,t3));
    b[0]=cadd(s0,s2); b[4]=csub(s0,s2); b[2]=cadd(s1,s3); b[6]=csub(s1,s3); }
  { cf s0 = cadd(u0,u2), s1 = csub(u0,u2), s2 = cadd(u1,u3), s3 = rot90<INV>(csub(u1,u3));
    b[1]=cadd(s0,s2); b[5]=csub(s0,s2); b[3]=cadd(s1,s3); b[7]=csub(s1,s3); }
}

// One radix-8 Stockham pass; j = butterfly id in [0,256).
template<int LOG2S, bool INV>
__device__ __forceinline__ void pass8f2(const float2* __restrict__ src,
                                        float2* __restrict__ dst, int j) {
  const int p = j >> LOG2S;
  cf a[8], b[8];
#pragma unroll
  for (int l = 0; l < 8; ++l) a[l] = ldx(src, j + (l << 8));
  dft8<INV>(a, b);
  const float ANG = -0.0030679615757712823f;  // -2*pi/2048
  float sn, cs;
  __sincosf(ANG * (float)(p << LOG2S), &sn, &cs);
  if (INV) sn = -sn;
  const cf w1{cs, sn};
  cf w = w1;
  b[1] = cmul(b[1], w);
#pragma unroll
  for (int k = 2; k < 8; ++k) { w = cmul(w, w1); b[k] = cmul(b[k], w); }
  const int wb = j + 7 * (p << LOG2S);
#pragma unroll
  for (int k = 0; k < 8; ++k) stx(dst, wb + (k << LOG2S), b[k]);
}

// Final radix-4 pass (s=512, twiddle-free): 512 butterflies, j in [0,256), 2 each.
template<bool INV>
__device__ __forceinline__ void pass4f2(const float2* __restrict__ src,
                                        float2* __restrict__ dst, int j) {
#pragma unroll
  for (int h = 0; h < 2; ++h) {
    const int jj = j + (h << 8);
    cf a0 = ldx(src, jj), a1 = ldx(src, jj + 512), a2 = ldx(src, jj + 1024), a3 = ldx(src, jj + 1536);
    cf s0 = cadd(a0,a2), s1 = csub(a0,a2), s2 = cadd(a1,a3), s3 = rot90<INV>(csub(a1,a3));
    stx(dst, jj,        cadd(s0,s2));
    stx(dst, jj + 512,  cadd(s1,s3));
    stx(dst, jj + 1024, csub(s0,s2));
    stx(dst, jj + 1536, csub(s1,s3));
  }
}

// load channel (q+ik packed) into Z; thread covers float4-groups j and j+256
__device__ __forceinline__ void loadch(const float* __restrict__ qp,
                                       const float* __restrict__ kp,
                                       float2* __restrict__ Z, int j) {
  const float4* q4 = (const float4*)qp;
  const float4* k4 = (const float4*)kp;
#pragma unroll
  for (int u = 0; u < 2; ++u) {
    const int g = j + (u << 8);
    const float4 vq = q4[g];
    const float4 vk = k4[g];
    const int base = g << 2;
    Z[swz(base + 0)] = {vq.x, vk.x};
    Z[swz(base + 1)] = {vq.y, vk.y};
    Z[swz(base + 2)] = {vq.z, vk.z};
    Z[swz(base + 3)] = {vq.w, vk.w};
  }
}

// Hermitian-split both packed fwd FFTs (Za,Zb) and build packed inverse input
// Zo = Sa + i*Sb over the FULL spectrum. All 512 threads; tasks f = t, t+512.
__device__ __forceinline__ void combine2(const float2* __restrict__ Za,
                                         const float2* __restrict__ Zb,
                                         float2* __restrict__ Zo, int t) {
#pragma unroll
  for (int u = 0; u < 2; ++u) {
    const int f = t + (u << 9);   // 0..1023
    if (f == 0) {
      const cf a0 = ldx(Za, 0), an = ldx(Za, 1024);
      const cf b0 = ldx(Zb, 0), bn = ldx(Zb, 1024);
      stx(Zo, 0,    {a0.r * a0.i, b0.r * b0.i});
      stx(Zo, 1024, {an.r * an.i, bn.r * bn.i});
    } else {
      const cf a = ldx(Za, f), am = ldx(Za, 2048 - f);
      const float aqr = 0.5f * (a.r + am.r), aqi = 0.5f * (a.i - am.i);
      const float akr = 0.5f * (a.i + am.i), aki = 0.5f * (am.r - a.r);
      const float sar = aqr * akr + aqi * aki, sai = aqi * akr - aqr * aki;
      const cf b = ldx(Zb, f), bm = ldx(Zb, 2048 - f);
      const float bqr = 0.5f * (b.r + bm.r), bqi = 0.5f * (b.i - bm.i);
      const float bkr = 0.5f * (b.i + bm.i), bki = 0.5f * (bm.r - b.r);
      const float sbr = bqr * bkr + bqi * bki, sbi = bqi * bkr - bqr * bki;
      stx(Zo, f,        {sar - sbi,  sai + sbr});
      stx(Zo, 2048 - f, {sar + sbi, -sai + sbr});
    }
  }
}

// store packed inverse result: Re -> channel c0 row, Im -> channel c1 row
__device__ __forceinline__ void storepair(const float2* __restrict__ Z,
                                          float* __restrict__ c0,
                                          float* __restrict__ c1, int j) {
  const float inv = 1.0f / (float)L_;
#pragma unroll
  for (int u = 0; u < 2; ++u) {
    const int g = j + (u << 8);
    const int base = g << 2;
    const float2 z0 = Z[swz(base + 0)];
    const float2 z1 = Z[swz(base + 1)];
    const float2 z2 = Z[swz(base + 2)];
    const float2 z3 = Z[swz(base + 3)];
    ((float4*)c0)[g] = make_float4(z0.x*inv, z1.x*inv, z2.x*inv, z3.x*inv);
    ((float4*)c1)[g] = make_float4(z0.y*inv, z1.y*inv, z2.y*inv, z3.y*inv);
  }
}

__global__ __launch_bounds__(512, 4) void kB(const float* __restrict__ qT,
                                             const float* __restrict__ kT,
                                             float* __restrict__ corrT) {
  __shared__ float2 U0[L_], U1[L_], U2[L_], U3[L_], U4[L_];   // 80 KiB
  const int t  = threadIdx.x;
  const int ch = t >> 8;        // 0 or 1 (wave-uniform)
  const int j  = t & 255;       // butterfly id within my FFT
  const size_t base = (size_t)blockIdx.x * 4 * L_;

  float2* ZD = ch ? U1 : U0;    // my data buffer
  float2* ZS = ch ? U3 : U2;    // my scratch buffer

  // ---- phase A: forward channels 0,1 (concurrent) ----
  loadch(qT + base + (size_t)ch * L_, kT + base + (size_t)ch * L_, ZD, j);
  __syncthreads();
  pass8f2<0, false>(ZD, ZS, j); __syncthreads();
  pass8f2<3, false>(ZS, ZD, j); __syncthreads();
  pass8f2<6, false>(ZD, ZS, j); __syncthreads();
  pass4f2<false>(ZS, ZD, j);    __syncthreads();
  combine2(U0, U1, U4, t);      __syncthreads();

  // ---- phase B: forward channels 2,3 (concurrent) ----
  loadch(qT + base + (size_t)(ch + 2) * L_, kT + base + (size_t)(ch + 2) * L_, ZD, j);
  __syncthreads();
  pass8f2<0, false>(ZD, ZS, j); __syncthreads();
  pass8f2<3, false>(ZS, ZD, j); __syncthreads();
  pass8f2<6, false>(ZD, ZS, j); __syncthreads();
  pass4f2<false>(ZS, ZD, j);    __syncthreads();
  combine2(U0, U1, U2, t);      __syncthreads();

  // ---- phase C: both packed inverses concurrently ----
  float2* Sp = ch ? U2 : U4;    // spectrum / result buffer
  float2* Tp = ch ? U1 : U0;    // ping-pong partner
  pass8f2<0, true>(Sp, Tp, j);  __syncthreads();
  pass8f2<3, true>(Tp, Sp, j);  __syncthreads();
  pass8f2<6, true>(Sp, Tp, j);  __syncthreads();
  pass4f2<true>(Tp, Sp, j);     __syncthreads();

  // ---- store: pair ch -> channels (2ch, 2ch+1) ----
  storepair(Sp, corrT + base + (size_t)(2 * ch) * L_,
                corrT + base + (size_t)(2 * ch + 1) * L_, j);
}

// ---------------------------------------------------------------------------
// Kernel C: transpose corrT (B,D,L) -> corr_out (B,L,D) + per-(b,dtile) sums.
// ---------------------------------------------------------------------------
__global__ __launch_bounds__(256) void kC(const float* __restrict__ corrT,
                                          float* __restrict__ corrOut,
                                          float* __restrict__ partial) {
  __shared__ float t[32][33];
  const int t0 = blockIdx.x * 32, d0 = blockIdx.y * 32, b = blockIdx.z;
  const int tx = threadIdx.x, ty = threadIdx.y;       // (32,8)
#pragma unroll
  for (int j = 0; j < 4; ++j) {
    const int d = d0 + ty + 8 * j;
    t[ty + 8 * j][tx] = corrT[((size_t)b * D_ + d) * L_ + t0 + tx];
  }
  __syncthreads();
#pragma unroll
  for (int j = 0; j < 4; ++j) {
    const int tt = t0 + ty + 8 * j;
    corrOut[((size_t)b * L_ + tt) * D_ + d0 + tx] = t[tx][ty + 8 * j];
  }
  if (ty == 0) {
    float s = 0.f;
#pragma unroll
    for (int i = 0; i < 32; ++i) s += t[i][tx];
    partial[((size_t)b * 16 + blockIdx.y) * L_ + t0 + tx] = s;
  }
}

// ---------------------------------------------------------------------------
// Kernel D0: reduce partial[256][L] -> g[L]  (32 blocks, deterministic)
// ---------------------------------------------------------------------------
__global__ __launch_bounds__(256) void kD0(const float* __restrict__ partial,
                                           float* __restrict__ g) {
  __shared__ float red[4][64];
  const int tl = threadIdx.x & 63, rg = threadIdx.x >> 6;
  const int tau = blockIdx.x * 64 + tl;
  float s = 0.f;
  for (int i = rg; i < 256; i += 4) s += partial[(size_t)i * L_ + tau];
  red[rg][tl] = s;
  __syncthreads();
  if (rg == 0) g[tau] = red[0][tl] + red[1][tl] + red[2][tl] + red[3][tl];
}

// ---------------------------------------------------------------------------
// Kernel D1: top-7 on g[L]; per-b softmax weights. Single small block.
// ---------------------------------------------------------------------------
__global__ __launch_bounds__(256) void kD1(const float* __restrict__ gin,
                                           const float* __restrict__ partial,
                                           int* __restrict__ oidx,
                                           float* __restrict__ ow) {
  __shared__ float g[L_];
  __shared__ float rv[256];
  __shared__ int   ri[256];
  __shared__ int   sidx[K_];
  const int tid = threadIdx.x;
#pragma unroll
  for (int u = 0; u < 8; ++u) g[tid + u * 256] = gin[tid + u * 256];
  __syncthreads();

  for (int it = 0; it < K_; ++it) {
    float bv = -1e30f; int bix = 1 << 30;
#pragma unroll
    for (int u = 0; u < 8; ++u) {
      const int tau = tid + u * 256;
      const float vv = g[tau];
      if (vv > bv || (vv == bv && tau < bix)) { bv = vv; bix = tau; }
    }
    rv[tid] = bv; ri[tid] = bix;
    __syncthreads();
    for (int off = 128; off > 0; off >>= 1) {
      if (tid < off) {
        const float v2 = rv[tid + off]; const int i2 = ri[tid + off];
        if (v2 > rv[tid] || (v2 == rv[tid] && i2 < ri[tid])) {
          rv[tid] = v2; ri[tid] = i2;
        }
      }
      __syncthreads();
    }
    if (tid == 0) { sidx[it] = ri[0]; g[ri[0]] = -3e38f; }
    __syncthreads();
  }

  if (tid < B_) {
    const int b = tid;
    float m[K_]; float mx = -1e30f;
    for (int kk = 0; kk < K_; ++kk) {
      float s = 0.f;
      for (int dt = 0; dt < 16; ++dt)
        s += partial[((size_t)b * 16 + dt) * L_ + sidx[kk]];
      m[kk] = s * (1.0f / 512.0f);
      mx = fmaxf(mx, m[kk]);
    }
    float sum = 0.f;
    for (int kk = 0; kk < K_; ++kk) { m[kk] = expf(m[kk] - mx); sum += m[kk]; }
    const float inv = 1.0f / sum;
    for (int kk = 0; kk < K_; ++kk) ow[b * K_ + kk] = m[kk] * inv;
  }
  if (tid < K_) oidx[tid] = sidx[tid];
}

// ---------------------------------------------------------------------------
// Kernel E: out[b,l,:] = sum_k w[b,k] * v[b, (l+idx[k])%L, :]   (float4)
// ---------------------------------------------------------------------------
__global__ __launch_bounds__(256) void kE(const float4* __restrict__ v4,
                                          const float* __restrict__ w,
                                          const int* __restrict__ idx,
                                          float4* __restrict__ out4) {
  const int bx = blockIdx.x;
  const int b  = bx >> 10;
  const int l  = ((bx & 1023) << 1) | (threadIdx.x >> 7);
  const int j  = threadIdx.x & 127;

  float ww[K_]; int rr[K_];
#pragma unroll
  for (int kk = 0; kk < K_; ++kk) {
    ww[kk] = w[b * K_ + kk];
    int r = l + idx[kk];
    if (r >= L_) r -= L_;
    rr[kk] = r;
  }
  const size_t vb = (size_t)b * L_ * 128;
  float4 acc = make_float4(0.f, 0.f, 0.f, 0.f);
#pragma unroll
  for (int kk = 0; kk < K_; ++kk) {
    const float4 vv = v4[vb + (size_t)rr[kk] * 128 + j];
    acc.x += ww[kk] * vv.x; acc.y += ww[kk] * vv.y;
    acc.z += ww[kk] * vv.z; acc.w += ww[kk] * vv.w;
  }
  out4[vb + (size_t)l * 128 + j] = acc;
}

// ---------------------------------------------------------------------------
extern "C" void kernel_launch(void* const* d_in, const int* in_sizes, int n_in,
                              void* d_out, int out_size, void* d_ws, size_t ws_size,
                              hipStream_t stream) {
  const float* q = (const float*)d_in[0];
  const float* k = (const float*)d_in[1];
  const float* v = (const float*)d_in[2];

  float* out     = (float*)d_out;        // final out  [0, Q_)
  float* corrOut = out + Q_;             // final corr [Q_, 2Q_)
  float* qT = out;                       // scratch: dead before kE overwrites
  float* kT = corrOut;                   // scratch: dead before kC overwrites

  float* corrT   = (float*)d_ws;                 // Q_ floats
  float* partial = corrT + Q_;                   // 524288 floats
  int*   oidx    = (int*)(partial + (size_t)B_ * 16 * L_);
  float* ow      = (float*)(oidx + 16);
  float* g2048   = corrT;                        // corrT dead after kC

  const dim3 thr(32, 8);
  kA<<<dim3(L_ / 32, D_ / 32, B_), thr, 0, stream>>>(q, k, qT, kT);
  kB<<<(B_ * D_) / 4, 512, 0, stream>>>(qT, kT, corrT);
  kC<<<dim3(L_ / 32, D_ / 32, B_), thr, 0, stream>>>(corrT, corrOut, partial);
  kD0<<<32, 256, 0, stream>>>(partial, g2048);
  kD1<<<1, 256, 0, stream>>>(g2048, partial, oidx, ow);
  kE<<<(B_ * L_) / 2, 256, 0, stream>>>((const float4*)v, ow, oidx, (float4*)out);
}

// Round 5
// 217.716 us; speedup vs baseline: 1.5471x; 1.5471x over previous
//
#include <hip/hip_runtime.h>
#include <math.h>

#define B_  16
#define L_  2048
#define D_  512
#define K_  7
#define Q_  (B_*L_*D_)   // 16777216 elements per output tensor

// ---------------------------------------------------------------------------
// Kernel A: tiled transpose (B,L,D) -> (B,D,L) for q and k.
// ---------------------------------------------------------------------------
__global__ __launch_bounds__(256) void kA(const float* __restrict__ q,
                                          const float* __restrict__ k,
                                          float* __restrict__ qT,
                                          float* __restrict__ kT) {
  __shared__ float tq[32][33];
  __shared__ float tk[32][33];
  const int l0 = blockIdx.x * 32, d0 = blockIdx.y * 32, b = blockIdx.z;
  const int tx = threadIdx.x, ty = threadIdx.y;       // (32,8)
  const size_t ibase = (size_t)b * L_ * D_;
#pragma unroll
  for (int j = 0; j < 4; ++j) {
    const int l = l0 + ty + 8 * j;
    tq[ty + 8 * j][tx] = q[ibase + (size_t)l * D_ + d0 + tx];
    tk[ty + 8 * j][tx] = k[ibase + (size_t)l * D_ + d0 + tx];
  }
  __syncthreads();
  const size_t obase = (size_t)b * D_ * L_;
#pragma unroll
  for (int j = 0; j < 4; ++j) {
    const int d = d0 + ty + 8 * j;
    qT[obase + (size_t)d * L_ + l0 + tx] = tq[tx][ty + 8 * j];
    kT[obase + (size_t)d * L_ + l0 + tx] = tk[tx][ty + 8 * j];
  }
}

// ---------------------------------------------------------------------------
// Kernel B: 2 channels per block, 256 threads, 32 KiB LDS (A,B ping-pong).
// ch0 fwd FFT -> spectrum S1 kept in REGISTERS -> ch1 fwd FFT -> combine
// (computes S2 on the fly from A, writes Z = S1 + i*S2 into B) -> packed
// inverse FFT -> Re/Im are the two channels' correlations.
// Mixed-radix (8,8,8,4) Stockham, float2 complex LDS, XOR swizzle.
// ---------------------------------------------------------------------------
struct cf { float r, i; };
__device__ __forceinline__ cf cadd(cf a, cf b){ return {a.r+b.r, a.i+b.i}; }
__device__ __forceinline__ cf csub(cf a, cf b){ return {a.r-b.r, a.i-b.i}; }
__device__ __forceinline__ cf cmul(cf a, cf b){ return {a.r*b.r - a.i*b.i, a.r*b.i + a.i*b.r}; }
template<bool INV> __device__ __forceinline__ cf rot90(cf x){
  return INV ? cf{-x.i, x.r} : cf{x.i, -x.r};   // * +/- i
}
__device__ __forceinline__ int swz(int a){ return a ^ (((a >> 4) ^ (a >> 8)) & 15); }
__device__ __forceinline__ cf ldx(const float2* __restrict__ p, int i){
  const float2 v = p[swz(i)]; return {v.x, v.y};
}
__device__ __forceinline__ void stx(float2* __restrict__ p, int i, cf v){
  p[swz(i)] = {v.r, v.i};
}

template<bool INV>
__device__ __forceinline__ void dft8(cf a[8], cf b[8]) {
  const float H = 0.70710678118654752440f;
  cf t0 = cadd(a[0],a[4]), t1 = cadd(a[1],a[5]), t2 = cadd(a[2],a[6]), t3 = cadd(a[3],a[7]);
  cf u0 = csub(a[0],a[4]), u1 = csub(a[1],a[5]), u2 = csub(a[2],a[6]), u3 = csub(a[3],a[7]);
  const cf w1 = INV ? cf{H,  H} : cf{ H, -H};
  const cf w3 = INV ? cf{-H, H} : cf{-H, -H};
  u1 = cmul(u1, w1);
  u2 = rot90<INV>(u2);
  u3 = cmul(u3, w3);
  { cf s0 = cadd(t0,t2), s1 = csub(t0,t2), s2 = cadd(t1,t3), s3 = rot90<INV>(csub(t1,t3));
    b[0]=cadd(s0,s2); b[4]=csub(s0,s2); b[2]=cadd(s1,s3); b[6]=csub(s1,s3); }
  { cf s0 = cadd(u0,u2), s1 = csub(u0,u2), s2 = cadd(u1,u3), s3 = rot90<INV>(csub(u1,u3));
    b[1]=cadd(s0,s2); b[5]=csub(s0,s2); b[3]=cadd(s1,s3); b[7]=csub(s1,s3); }
}

template<int LOG2S, bool INV>
__device__ __forceinline__ void pass8f2(const float2* __restrict__ src,
                                        float2* __restrict__ dst, int j) {
  const int p = j >> LOG2S;
  cf a[8], b[8];
#pragma unroll
  for (int l = 0; l < 8; ++l) a[l] = ldx(src, j + (l << 8));
  dft8<INV>(a, b);
  const float ANG = -0.0030679615757712823f;  // -2*pi/2048
  float sn, cs;
  __sincosf(ANG * (float)(p << LOG2S), &sn, &cs);
  if (INV) sn = -sn;
  const cf w1{cs, sn};
  cf w = w1;
  b[1] = cmul(b[1], w);
#pragma unroll
  for (int k = 2; k < 8; ++k) { w = cmul(w, w1); b[k] = cmul(b[k], w); }
  const int wb = j + 7 * (p << LOG2S);
#pragma unroll
  for (int k = 0; k < 8; ++k) stx(dst, wb + (k << LOG2S), b[k]);
}

template<bool INV>
__device__ __forceinline__ void pass4f2(const float2* __restrict__ src,
                                        float2* __restrict__ dst, int j) {
#pragma unroll
  for (int h = 0; h < 2; ++h) {
    const int jj = j + (h << 8);
    cf a0 = ldx(src, jj), a1 = ldx(src, jj + 512), a2 = ldx(src, jj + 1024), a3 = ldx(src, jj + 1536);
    cf s0 = cadd(a0,a2), s1 = csub(a0,a2), s2 = cadd(a1,a3), s3 = rot90<INV>(csub(a1,a3));
    stx(dst, jj,        cadd(s0,s2));
    stx(dst, jj + 512,  cadd(s1,s3));
    stx(dst, jj + 1024, csub(s0,s2));
    stx(dst, jj + 1536, csub(s1,s3));
  }
}

__device__ __forceinline__ void load_ch(const float* __restrict__ qp,
                                        const float* __restrict__ kp,
                                        float2* __restrict__ Z, int tid) {
#pragma unroll
  for (int u = 0; u < 2; ++u) {
    const int i4 = tid + (u << 8);
    const float4 vq = ((const float4*)qp)[i4];
    const float4 vk = ((const float4*)kp)[i4];
    const int base = i4 << 2;
    Z[swz(base + 0)] = {vq.x, vk.x};
    Z[swz(base + 1)] = {vq.y, vk.y};
    Z[swz(base + 2)] = {vq.z, vk.z};
    Z[swz(base + 3)] = {vq.w, vk.w};
  }
}

__device__ __forceinline__ void store2(const float2* __restrict__ Z,
                                       float* __restrict__ c0,
                                       float* __restrict__ c1, int tid) {
  const float inv = 1.0f / (float)L_;
#pragma unroll
  for (int u = 0; u < 2; ++u) {
    const int i4 = tid + (u << 8);
    const int base = i4 << 2;
    const float2 z0 = Z[swz(base + 0)];
    const float2 z1 = Z[swz(base + 1)];
    const float2 z2 = Z[swz(base + 2)];
    const float2 z3 = Z[swz(base + 3)];
    ((float4*)c0)[i4] = make_float4(z0.x*inv, z1.x*inv, z2.x*inv, z3.x*inv);
    ((float4*)c1)[i4] = make_float4(z0.y*inv, z1.y*inv, z2.y*inv, z3.y*inv);
  }
}

__global__ __launch_bounds__(256) void kB(const float* __restrict__ qT,
                                          const float* __restrict__ kT,
                                          float* __restrict__ corrT) {
  __shared__ float2 A[L_];    // 16 KiB
  __shared__ float2 Bb[L_];   // 16 KiB   (32 KiB total)
  const int tid = threadIdx.x;
  const size_t row0 = (size_t)(blockIdx.x * 2) * L_;
  const size_t row1 = row0 + L_;

  // ---- channel 0 forward (ends in A) ----
  load_ch(qT + row0, kT + row0, A, tid);  __syncthreads();
  pass8f2<0, false>(A, Bb, tid);          __syncthreads();
  pass8f2<3, false>(Bb, A, tid);          __syncthreads();
  pass8f2<6, false>(A, Bb, tid);          __syncthreads();
  pass4f2<false>(Bb, A, tid);             __syncthreads();

  // ---- spectrum S1 = Q0*conj(K0) into registers (f = tid + 256u) ----
  float s1r[4], s1i[4];
#pragma unroll
  for (int u = 0; u < 4; ++u) {
    const int f = tid + (u << 8);
    if (f == 0) {
      const cf z0 = ldx(A, 0), zn = ldx(A, 1024);
      s1r[u] = z0.r * z0.i;       // S1[0]    (real)
      s1i[u] = zn.r * zn.i;       // S1[1024] (real), packed here
    } else {
      const cf a = ldx(A, f), am = ldx(A, 2048 - f);
      const float qr = 0.5f * (a.r + am.r), qi = 0.5f * (a.i - am.i);
      const float kr = 0.5f * (a.i + am.i), ki = 0.5f * (am.r - a.r);
      s1r[u] = qr * kr + qi * ki;
      s1i[u] = qi * kr - qr * ki;
    }
  }
  __syncthreads();

  // ---- channel 1 forward (ends in A) ----
  load_ch(qT + row1, kT + row1, A, tid);  __syncthreads();
  pass8f2<0, false>(A, Bb, tid);          __syncthreads();
  pass8f2<3, false>(Bb, A, tid);          __syncthreads();
  pass8f2<6, false>(A, Bb, tid);          __syncthreads();
  pass4f2<false>(Bb, A, tid);             __syncthreads();

  // ---- combine: S2 from A on the fly; write Z = S1 + i*S2 into Bb ----
#pragma unroll
  for (int u = 0; u < 4; ++u) {
    const int f = tid + (u << 8);
    if (f == 0) {
      const cf z0 = ldx(A, 0), zn = ldx(A, 1024);
      const float s2_0 = z0.r * z0.i, s2_n = zn.r * zn.i;
      stx(Bb, 0,    {s1r[0], s2_0});
      stx(Bb, 1024, {s1i[0], s2_n});
    } else {
      const cf a = ldx(A, f), am = ldx(A, 2048 - f);
      const float qr = 0.5f * (a.r + am.r), qi = 0.5f * (a.i - am.i);
      const float kr = 0.5f * (a.i + am.i), ki = 0.5f * (am.r - a.r);
      const float s2r = qr * kr + qi * ki, s2i = qi * kr - qr * ki;
      stx(Bb, f,        {s1r[u] - s2i,  s1i[u] + s2r});
      stx(Bb, 2048 - f, {s1r[u] + s2i, -s1i[u] + s2r});
    }
  }
  __syncthreads();

  // ---- packed inverse (ends in Bb) ----
  pass8f2<0, true>(Bb, A, tid);           __syncthreads();
  pass8f2<3, true>(A, Bb, tid);           __syncthreads();
  pass8f2<6, true>(Bb, A, tid);           __syncthreads();
  pass4f2<true>(A, Bb, tid);              __syncthreads();

  store2(Bb, corrT + row0, corrT + row1, tid);
}

// ---------------------------------------------------------------------------
// Kernel C: transpose corrT (B,D,L) -> corr_out (B,L,D) + per-(b,dtile) sums.
// ---------------------------------------------------------------------------
__global__ __launch_bounds__(256) void kC(const float* __restrict__ corrT,
                                          float* __restrict__ corrOut,
                                          float* __restrict__ partial) {
  __shared__ float t[32][33];
  const int t0 = blockIdx.x * 32, d0 = blockIdx.y * 32, b = blockIdx.z;
  const int tx = threadIdx.x, ty = threadIdx.y;       // (32,8)
#pragma unroll
  for (int j = 0; j < 4; ++j) {
    const int d = d0 + ty + 8 * j;
    t[ty + 8 * j][tx] = corrT[((size_t)b * D_ + d) * L_ + t0 + tx];
  }
  __syncthreads();
#pragma unroll
  for (int j = 0; j < 4; ++j) {
    const int tt = t0 + ty + 8 * j;
    corrOut[((size_t)b * L_ + tt) * D_ + d0 + tx] = t[tx][ty + 8 * j];
  }
  if (ty == 0) {
    float s = 0.f;
#pragma unroll
    for (int i = 0; i < 32; ++i) s += t[i][tx];
    partial[((size_t)b * 16 + blockIdx.y) * L_ + t0 + tx] = s;
  }
}

// ---------------------------------------------------------------------------
// Kernel D0: reduce partial[256][L] -> g[L]  (32 blocks, deterministic)
// ---------------------------------------------------------------------------
__global__ __launch_bounds__(256) void kD0(const float* __restrict__ partial,
                                           float* __restrict__ g) {
  __shared__ float red[4][64];
  const int tl = threadIdx.x & 63, rg = threadIdx.x >> 6;
  const int tau = blockIdx.x * 64 + tl;
  float s = 0.f;
  for (int i = rg; i < 256; i += 4) s += partial[(size_t)i * L_ + tau];
  red[rg][tl] = s;
  __syncthreads();
  if (rg == 0) g[tau] = red[0][tl] + red[1][tl] + red[2][tl] + red[3][tl];
}

// ---------------------------------------------------------------------------
// Kernel D1: top-7 on g[L]; per-b softmax weights. Single small block.
// ---------------------------------------------------------------------------
__global__ __launch_bounds__(256) void kD1(const float* __restrict__ gin,
                                           const float* __restrict__ partial,
                                           int* __restrict__ oidx,
                                           float* __restrict__ ow) {
  __shared__ float g[L_];
  __shared__ float rv[256];
  __shared__ int   ri[256];
  __shared__ int   sidx[K_];
  const int tid = threadIdx.x;
#pragma unroll
  for (int u = 0; u < 8; ++u) g[tid + u * 256] = gin[tid + u * 256];
  __syncthreads();

  for (int it = 0; it < K_; ++it) {
    float bv = -1e30f; int bix = 1 << 30;
#pragma unroll
    for (int u = 0; u < 8; ++u) {
      const int tau = tid + u * 256;
      const float vv = g[tau];
      if (vv > bv || (vv == bv && tau < bix)) { bv = vv; bix = tau; }
    }
    rv[tid] = bv; ri[tid] = bix;
    __syncthreads();
    for (int off = 128; off > 0; off >>= 1) {
      if (tid < off) {
        const float v2 = rv[tid + off]; const int i2 = ri[tid + off];
        if (v2 > rv[tid] || (v2 == rv[tid] && i2 < ri[tid])) {
          rv[tid] = v2; ri[tid] = i2;
        }
      }
      __syncthreads();
    }
    if (tid == 0) { sidx[it] = ri[0]; g[ri[0]] = -3e38f; }
    __syncthreads();
  }

  if (tid < B_) {
    const int b = tid;
    float m[K_]; float mx = -1e30f;
    for (int kk = 0; kk < K_; ++kk) {
      float s = 0.f;
      for (int dt = 0; dt < 16; ++dt)
        s += partial[((size_t)b * 16 + dt) * L_ + sidx[kk]];
      m[kk] = s * (1.0f / 512.0f);
      mx = fmaxf(mx, m[kk]);
    }
    float sum = 0.f;
    for (int kk = 0; kk < K_; ++kk) { m[kk] = expf(m[kk] - mx); sum += m[kk]; }
    const float inv = 1.0f / sum;
    for (int kk = 0; kk < K_; ++kk) ow[b * K_ + kk] = m[kk] * inv;
  }
  if (tid < K_) oidx[tid] = sidx[tid];
}

// ---------------------------------------------------------------------------
// Kernel E: out[b,l,:] = sum_k w[b,k] * v[b, (l+idx[k])%L, :]   (float4)
// ---------------------------------------------------------------------------
__global__ __launch_bounds__(256) void kE(const float4* __restrict__ v4,
                                          const float* __restrict__ w,
                                          const int* __restrict__ idx,
                                          float4* __restrict__ out4) {
  const int bx = blockIdx.x;
  const int b  = bx >> 10;
  const int l  = ((bx & 1023) << 1) | (threadIdx.x >> 7);
  const int j  = threadIdx.x & 127;

  float ww[K_]; int rr[K_];
#pragma unroll
  for (int kk = 0; kk < K_; ++kk) {
    ww[kk] = w[b * K_ + kk];
    int r = l + idx[kk];
    if (r >= L_) r -= L_;
    rr[kk] = r;
  }
  const size_t vb = (size_t)b * L_ * 128;
  float4 acc = make_float4(0.f, 0.f, 0.f, 0.f);
#pragma unroll
  for (int kk = 0; kk < K_; ++kk) {
    const float4 vv = v4[vb + (size_t)rr[kk] * 128 + j];
    acc.x += ww[kk] * vv.x; acc.y += ww[kk] * vv.y;
    acc.z += ww[kk] * vv.z; acc.w += ww[kk] * vv.w;
  }
  out4[vb + (size_t)l * 128 + j] = acc;
}

// ---------------------------------------------------------------------------
extern "C" void kernel_launch(void* const* d_in, const int* in_sizes, int n_in,
                              void* d_out, int out_size, void* d_ws, size_t ws_size,
                              hipStream_t stream) {
  const float* q = (const float*)d_in[0];
  const float* k = (const float*)d_in[1];
  const float* v = (const float*)d_in[2];

  float* out     = (float*)d_out;        // final out  [0, Q_)
  float* corrOut = out + Q_;             // final corr [Q_, 2Q_)
  float* qT = out;                       // scratch: dead before kE overwrites
  float* kT = corrOut;                   // scratch: dead before kC overwrites

  float* corrT   = (float*)d_ws;                 // Q_ floats
  float* partial = corrT + Q_;                   // 524288 floats
  int*   oidx    = (int*)(partial + (size_t)B_ * 16 * L_);
  float* ow      = (float*)(oidx + 16);
  float* g2048   = corrT;                        // corrT dead after kC

  const dim3 thr(32, 8);
  kA<<<dim3(L_ / 32, D_ / 32, B_), thr, 0, stream>>>(q, k, qT, kT);
  kB<<<(B_ * D_) / 2, 256, 0, stream>>>(qT, kT, corrT);
  kC<<<dim3(L_ / 32, D_ / 32, B_), thr, 0, stream>>>(corrT, corrOut, partial);
  kD0<<<32, 256, 0, stream>>>(partial, g2048);
  kD1<<<1, 256, 0, stream>>>(g2048, partial, oidx, ow);
  kE<<<(B_ * L_) / 2, 256, 0, stream>>>((const float4*)v, ow, oidx, (float4*)out);
}

// Round 6
// 211.818 us; speedup vs baseline: 1.5902x; 1.0278x over previous
//
#include <hip/hip_runtime.h>
#include <math.h>

#define B_  16
#define L_  2048
#define D_  512
#define K_  7
#define Q_  (B_*L_*D_)   // 16777216 elements per output tensor

// ---------------------------------------------------------------------------
// Kernel A: tiled transpose (B,L,D) -> (B,D,L) for q and k.
// ---------------------------------------------------------------------------
__global__ __launch_bounds__(256) void kA(const float* __restrict__ q,
                                          const float* __restrict__ k,
                                          float* __restrict__ qT,
                                          float* __restrict__ kT) {
  __shared__ float tq[32][33];
  __shared__ float tk[32][33];
  const int l0 = blockIdx.x * 32, d0 = blockIdx.y * 32, b = blockIdx.z;
  const int tx = threadIdx.x, ty = threadIdx.y;       // (32,8)
  const size_t ibase = (size_t)b * L_ * D_;
#pragma unroll
  for (int j = 0; j < 4; ++j) {
    const int l = l0 + ty + 8 * j;
    tq[ty + 8 * j][tx] = q[ibase + (size_t)l * D_ + d0 + tx];
    tk[ty + 8 * j][tx] = k[ibase + (size_t)l * D_ + d0 + tx];
  }
  __syncthreads();
  const size_t obase = (size_t)b * D_ * L_;
#pragma unroll
  for (int j = 0; j < 4; ++j) {
    const int d = d0 + ty + 8 * j;
    qT[obase + (size_t)d * L_ + l0 + tx] = tq[tx][ty + 8 * j];
    kT[obase + (size_t)d * L_ + l0 + tx] = tk[tx][ty + 8 * j];
  }
}

// ---------------------------------------------------------------------------
// Kernel B: 2 channels/block, 256 threads, 32 KiB LDS (A,B ping-pong).
// Forward pass-1 fused with the global load (z = q + i*k read directly in
// butterfly order); inverse last pass fused with the global store.
// S1 spectrum lives in registers across the ch1 FFT. 12 barriers total.
// Mixed-radix (8,8,8,4) Stockham, float2 complex LDS, XOR swizzle.
// ---------------------------------------------------------------------------
struct cf { float r, i; };
__device__ __forceinline__ cf cadd(cf a, cf b){ return {a.r+b.r, a.i+b.i}; }
__device__ __forceinline__ cf csub(cf a, cf b){ return {a.r-b.r, a.i-b.i}; }
__device__ __forceinline__ cf cmul(cf a, cf b){ return {a.r*b.r - a.i*b.i, a.r*b.i + a.i*b.r}; }
template<bool INV> __device__ __forceinline__ cf rot90(cf x){
  return INV ? cf{-x.i, x.r} : cf{x.i, -x.r};   // * +/- i
}
__device__ __forceinline__ int swz(int a){ return a ^ (((a >> 4) ^ (a >> 8)) & 15); }
__device__ __forceinline__ cf ldx(const float2* __restrict__ p, int i){
  const float2 v = p[swz(i)]; return {v.x, v.y};
}
__device__ __forceinline__ void stx(float2* __restrict__ p, int i, cf v){
  p[swz(i)] = {v.r, v.i};
}

template<bool INV>
__device__ __forceinline__ void dft8(cf a[8], cf b[8]) {
  const float H = 0.70710678118654752440f;
  cf t0 = cadd(a[0],a[4]), t1 = cadd(a[1],a[5]), t2 = cadd(a[2],a[6]), t3 = cadd(a[3],a[7]);
  cf u0 = csub(a[0],a[4]), u1 = csub(a[1],a[5]), u2 = csub(a[2],a[6]), u3 = csub(a[3],a[7]);
  const cf w1 = INV ? cf{H,  H} : cf{ H, -H};
  const cf w3 = INV ? cf{-H, H} : cf{-H, -H};
  u1 = cmul(u1, w1);
  u2 = rot90<INV>(u2);
  u3 = cmul(u3, w3);
  { cf s0 = cadd(t0,t2), s1 = csub(t0,t2), s2 = cadd(t1,t3), s3 = rot90<INV>(csub(t1,t3));
    b[0]=cadd(s0,s2); b[4]=csub(s0,s2); b[2]=cadd(s1,s3); b[6]=csub(s1,s3); }
  { cf s0 = cadd(u0,u2), s1 = csub(u0,u2), s2 = cadd(u1,u3), s3 = rot90<INV>(csub(u1,u3));
    b[1]=cadd(s0,s2); b[5]=csub(s0,s2); b[3]=cadd(s1,s3); b[7]=csub(s1,s3); }
}

// Apply twiddles w^1..w^7 (log-depth chain) and store (Stockham scatter).
template<int LOG2S>
__device__ __forceinline__ void twiddle_store(cf b[8], float2* __restrict__ dst,
                                              int j, int p, float sgn_ang) {
  float sn, cs;
  __sincosf(sgn_ang * (float)(p << LOG2S), &sn, &cs);
  const cf w1{cs, sn};
  const cf w2 = cmul(w1, w1);
  const cf w3 = cmul(w2, w1);
  const cf w4 = cmul(w2, w2);
  const cf w5 = cmul(w3, w2);
  const cf w6 = cmul(w3, w3);
  const cf w7 = cmul(w4, w3);
  b[1] = cmul(b[1], w1); b[2] = cmul(b[2], w2); b[3] = cmul(b[3], w3);
  b[4] = cmul(b[4], w4); b[5] = cmul(b[5], w5); b[6] = cmul(b[6], w6);
  b[7] = cmul(b[7], w7);
  const int wb = j + 7 * (p << LOG2S);
#pragma unroll
  for (int k = 0; k < 8; ++k) stx(dst, wb + (k << LOG2S), b[k]);
}

#define ANG_ (-0.0030679615757712823f)   // -2*pi/2048

// Forward pass 1 fused with global load: z[l] = q[l] + i*k[l].
__device__ __forceinline__ void pass8_first(const float* __restrict__ qg,
                                            const float* __restrict__ kg,
                                            float2* __restrict__ dst, int j) {
  cf a[8], b[8];
#pragma unroll
  for (int l = 0; l < 8; ++l) {
    const int ix = j + (l << 8);
    a[l] = {qg[ix], kg[ix]};
  }
  dft8<false>(a, b);
  twiddle_store<0>(b, dst, j, j, ANG_);
}

template<int LOG2S, bool INV>
__device__ __forceinline__ void pass8f2(const float2* __restrict__ src,
                                        float2* __restrict__ dst, int j) {
  const int p = j >> LOG2S;
  cf a[8], b[8];
#pragma unroll
  for (int l = 0; l < 8; ++l) a[l] = ldx(src, j + (l << 8));
  dft8<INV>(a, b);
  twiddle_store<LOG2S>(b, dst, j, p, INV ? -ANG_ : ANG_);
}

// Forward final radix-4 (s=512, twiddle-free), LDS->LDS.
__device__ __forceinline__ void pass4_fwd(const float2* __restrict__ src,
                                          float2* __restrict__ dst, int j) {
#pragma unroll
  for (int h = 0; h < 2; ++h) {
    const int jj = j + (h << 8);
    cf a0 = ldx(src, jj), a1 = ldx(src, jj + 512), a2 = ldx(src, jj + 1024), a3 = ldx(src, jj + 1536);
    cf s0 = cadd(a0,a2), s1 = csub(a0,a2), s2 = cadd(a1,a3), s3 = rot90<false>(csub(a1,a3));
    stx(dst, jj,        cadd(s0,s2));
    stx(dst, jj + 512,  cadd(s1,s3));
    stx(dst, jj + 1024, csub(s0,s2));
    stx(dst, jj + 1536, csub(s1,s3));
  }
}

// Inverse final radix-4 fused with the global store (Re->c0, Im->c1).
__device__ __forceinline__ void pass4_last(const float2* __restrict__ src,
                                           float* __restrict__ c0,
                                           float* __restrict__ c1, int j) {
  const float inv = 1.0f / (float)L_;
#pragma unroll
  for (int h = 0; h < 2; ++h) {
    const int jj = j + (h << 8);
    cf a0 = ldx(src, jj), a1 = ldx(src, jj + 512), a2 = ldx(src, jj + 1024), a3 = ldx(src, jj + 1536);
    cf s0 = cadd(a0,a2), s1 = csub(a0,a2), s2 = cadd(a1,a3), s3 = rot90<true>(csub(a1,a3));
    const cf o0 = cadd(s0,s2), o1 = cadd(s1,s3), o2 = csub(s0,s2), o3 = csub(s1,s3);
    c0[jj]        = o0.r * inv;  c1[jj]        = o0.i * inv;
    c0[jj + 512]  = o1.r * inv;  c1[jj + 512]  = o1.i * inv;
    c0[jj + 1024] = o2.r * inv;  c1[jj + 1024] = o2.i * inv;
    c0[jj + 1536] = o3.r * inv;  c1[jj + 1536] = o3.i * inv;
  }
}

__global__ __launch_bounds__(256) void kB(const float* __restrict__ qT,
                                          const float* __restrict__ kT,
                                          float* __restrict__ corrT) {
  __shared__ float2 A[L_];    // 16 KiB
  __shared__ float2 Bb[L_];   // 16 KiB   (32 KiB total)
  const int tid = threadIdx.x;
  const size_t row0 = (size_t)(blockIdx.x * 2) * L_;
  const size_t row1 = row0 + L_;

  // ---- channel 0 forward (global->pass1->Bb ... ends in A) ----
  pass8_first(qT + row0, kT + row0, Bb, tid); __syncthreads();
  pass8f2<3, false>(Bb, A, tid);              __syncthreads();
  pass8f2<6, false>(A, Bb, tid);              __syncthreads();
  pass4_fwd(Bb, A, tid);                      __syncthreads();

  // ---- spectrum S1 = Q0*conj(K0) into registers (f = tid + 256u) ----
  float s1r[4], s1i[4];
#pragma unroll
  for (int u = 0; u < 4; ++u) {
    const int f = tid + (u << 8);
    if (f == 0) {
      const cf z0 = ldx(A, 0), zn = ldx(A, 1024);
      s1r[u] = z0.r * z0.i;       // S1[0]    (real)
      s1i[u] = zn.r * zn.i;       // S1[1024] (real), packed here
    } else {
      const cf a = ldx(A, f), am = ldx(A, 2048 - f);
      const float qr = 0.5f * (a.r + am.r), qi = 0.5f * (a.i - am.i);
      const float kr = 0.5f * (a.i + am.i), ki = 0.5f * (am.r - a.r);
      s1r[u] = qr * kr + qi * ki;
      s1i[u] = qi * kr - qr * ki;
    }
  }
  // no barrier: next write is Bb (fenced by the barrier after pass8_first);
  // the next write to A (pass8f2<3>) is fenced by that same barrier.

  // ---- channel 1 forward (ends in A) ----
  pass8_first(qT + row1, kT + row1, Bb, tid); __syncthreads();
  pass8f2<3, false>(Bb, A, tid);              __syncthreads();
  pass8f2<6, false>(A, Bb, tid);              __syncthreads();
  pass4_fwd(Bb, A, tid);                      __syncthreads();

  // ---- combine: S2 from A on the fly; write Z = S1 + i*S2 into Bb ----
#pragma unroll
  for (int u = 0; u < 4; ++u) {
    const int f = tid + (u << 8);
    if (f == 0) {
      const cf z0 = ldx(A, 0), zn = ldx(A, 1024);
      const float s2_0 = z0.r * z0.i, s2_n = zn.r * zn.i;
      stx(Bb, 0,    {s1r[0], s2_0});
      stx(Bb, 1024, {s1i[0], s2_n});
    } else {
      const cf a = ldx(A, f), am = ldx(A, 2048 - f);
      const float qr = 0.5f * (a.r + am.r), qi = 0.5f * (a.i - am.i);
      const float kr = 0.5f * (a.i + am.i), ki = 0.5f * (am.r - a.r);
      const float s2r = qr * kr + qi * ki, s2i = qi * kr - qr * ki;
      stx(Bb, f,        {s1r[u] - s2i,  s1i[u] + s2r});
      stx(Bb, 2048 - f, {s1r[u] + s2i, -s1i[u] + s2r});
    }
  }
  __syncthreads();

  // ---- packed inverse; last pass stores straight to global ----
  pass8f2<0, true>(Bb, A, tid);               __syncthreads();
  pass8f2<3, true>(A, Bb, tid);               __syncthreads();
  pass8f2<6, true>(Bb, A, tid);               __syncthreads();
  pass4_last(A, corrT + row0, corrT + row1, tid);
}

// ---------------------------------------------------------------------------
// Kernel C: transpose corrT (B,D,L) -> corr_out (B,L,D) + per-(b,dtile) sums.
// ---------------------------------------------------------------------------
__global__ __launch_bounds__(256) void kC(const float* __restrict__ corrT,
                                          float* __restrict__ corrOut,
                                          float* __restrict__ partial) {
  __shared__ float t[32][33];
  const int t0 = blockIdx.x * 32, d0 = blockIdx.y * 32, b = blockIdx.z;
  const int tx = threadIdx.x, ty = threadIdx.y;       // (32,8)
#pragma unroll
  for (int j = 0; j < 4; ++j) {
    const int d = d0 + ty + 8 * j;
    t[ty + 8 * j][tx] = corrT[((size_t)b * D_ + d) * L_ + t0 + tx];
  }
  __syncthreads();
#pragma unroll
  for (int j = 0; j < 4; ++j) {
    const int tt = t0 + ty + 8 * j;
    corrOut[((size_t)b * L_ + tt) * D_ + d0 + tx] = t[tx][ty + 8 * j];
  }
  if (ty == 0) {
    float s = 0.f;
#pragma unroll
    for (int i = 0; i < 32; ++i) s += t[i][tx];
    partial[((size_t)b * 16 + blockIdx.y) * L_ + t0 + tx] = s;
  }
}

// ---------------------------------------------------------------------------
// Kernel D0: reduce partial[256][L] -> g[L]  (32 blocks, deterministic)
// ---------------------------------------------------------------------------
__global__ __launch_bounds__(256) void kD0(const float* __restrict__ partial,
                                           float* __restrict__ g) {
  __shared__ float red[4][64];
  const int tl = threadIdx.x & 63, rg = threadIdx.x >> 6;
  const int tau = blockIdx.x * 64 + tl;
  float s = 0.f;
  for (int i = rg; i < 256; i += 4) s += partial[(size_t)i * L_ + tau];
  red[rg][tl] = s;
  __syncthreads();
  if (rg == 0) g[tau] = red[0][tl] + red[1][tl] + red[2][tl] + red[3][tl];
}

// ---------------------------------------------------------------------------
// Kernel D1: top-7 on g[L]; per-b softmax weights. Single small block.
// ---------------------------------------------------------------------------
__global__ __launch_bounds__(256) void kD1(const float* __restrict__ gin,
                                           const float* __restrict__ partial,
                                           int* __restrict__ oidx,
                                           float* __restrict__ ow) {
  __shared__ float g[L_];
  __shared__ float rv[256];
  __shared__ int   ri[256];
  __shared__ int   sidx[K_];
  const int tid = threadIdx.x;
#pragma unroll
  for (int u = 0; u < 8; ++u) g[tid + u * 256] = gin[tid + u * 256];
  __syncthreads();

  for (int it = 0; it < K_; ++it) {
    float bv = -1e30f; int bix = 1 << 30;
#pragma unroll
    for (int u = 0; u < 8; ++u) {
      const int tau = tid + u * 256;
      const float vv = g[tau];
      if (vv > bv || (vv == bv && tau < bix)) { bv = vv; bix = tau; }
    }
    rv[tid] = bv; ri[tid] = bix;
    __syncthreads();
    for (int off = 128; off > 0; off >>= 1) {
      if (tid < off) {
        const float v2 = rv[tid + off]; const int i2 = ri[tid + off];
        if (v2 > rv[tid] || (v2 == rv[tid] && i2 < ri[tid])) {
          rv[tid] = v2; ri[tid] = i2;
        }
      }
      __syncthreads();
    }
    if (tid == 0) { sidx[it] = ri[0]; g[ri[0]] = -3e38f; }
    __syncthreads();
  }

  if (tid < B_) {
    const int b = tid;
    float m[K_]; float mx = -1e30f;
    for (int kk = 0; kk < K_; ++kk) {
      float s = 0.f;
      for (int dt = 0; dt < 16; ++dt)
        s += partial[((size_t)b * 16 + dt) * L_ + sidx[kk]];
      m[kk] = s * (1.0f / 512.0f);
      mx = fmaxf(mx, m[kk]);
    }
    float sum = 0.f;
    for (int kk = 0; kk < K_; ++kk) { m[kk] = expf(m[kk] - mx); sum += m[kk]; }
    const float inv = 1.0f / sum;
    for (int kk = 0; kk < K_; ++kk) ow[b * K_ + kk] = m[kk] * inv;
  }
  if (tid < K_) oidx[tid] = sidx[tid];
}

// ---------------------------------------------------------------------------
// Kernel E: out[b,l,:] = sum_k w[b,k] * v[b, (l+idx[k])%L, :]   (float4)
// ---------------------------------------------------------------------------
__global__ __launch_bounds__(256) void kE(const float4* __restrict__ v4,
                                          const float* __restrict__ w,
                                          const int* __restrict__ idx,
                                          float4* __restrict__ out4) {
  const int bx = blockIdx.x;
  const int b  = bx >> 10;
  const int l  = ((bx & 1023) << 1) | (threadIdx.x >> 7);
  const int j  = threadIdx.x & 127;

  float ww[K_]; int rr[K_];
#pragma unroll
  for (int kk = 0; kk < K_; ++kk) {
    ww[kk] = w[b * K_ + kk];
    int r = l + idx[kk];
    if (r >= L_) r -= L_;
    rr[kk] = r;
  }
  const size_t vb = (size_t)b * L_ * 128;
  float4 acc = make_float4(0.f, 0.f, 0.f, 0.f);
#pragma unroll
  for (int kk = 0; kk < K_; ++kk) {
    const float4 vv = v4[vb + (size_t)rr[kk] * 128 + j];
    acc.x += ww[kk] * vv.x; acc.y += ww[kk] * vv.y;
    acc.z += ww[kk] * vv.z; acc.w += ww[kk] * vv.w;
  }
  out4[vb + (size_t)l * 128 + j] = acc;
}

// ---------------------------------------------------------------------------
extern "C" void kernel_launch(void* const* d_in, const int* in_sizes, int n_in,
                              void* d_out, int out_size, void* d_ws, size_t ws_size,
                              hipStream_t stream) {
  const float* q = (const float*)d_in[0];
  const float* k = (const float*)d_in[1];
  const float* v = (const float*)d_in[2];

  float* out     = (float*)d_out;        // final out  [0, Q_)
  float* corrOut = out + Q_;             // final corr [Q_, 2Q_)
  float* qT = out;                       // scratch: dead before kE overwrites
  float* kT = corrOut;                   // scratch: dead before kC overwrites

  float* corrT   = (float*)d_ws;                 // Q_ floats
  float* partial = corrT + Q_;                   // 524288 floats
  int*   oidx    = (int*)(partial + (size_t)B_ * 16 * L_);
  float* ow      = (float*)(oidx + 16);
  float* g2048   = corrT;                        // corrT dead after kC

  const dim3 thr(32, 8);
  kA<<<dim3(L_ / 32, D_ / 32, B_), thr, 0, stream>>>(q, k, qT, kT);
  kB<<<(B_ * D_) / 2, 256, 0, stream>>>(qT, kT, corrT);
  kC<<<dim3(L_ / 32, D_ / 32, B_), thr, 0, stream>>>(corrT, corrOut, partial);
  kD0<<<32, 256, 0, stream>>>(partial, g2048);
  kD1<<<1, 256, 0, stream>>>(g2048, partial, oidx, ow);
  kE<<<(B_ * L_) / 2, 256, 0, stream>>>((const float4*)v, ow, oidx, (float4*)out);
}

// Round 7
// 201.822 us; speedup vs baseline: 1.6690x; 1.0495x over previous
//
#include <hip/hip_runtime.h>
#include <math.h>

#define B_  16
#define L_  2048
#define D_  512
#define K_  7
#define Q_  (B_*L_*D_)   // 16777216 elements per output tensor

// ---------------------------------------------------------------------------
// Kernel A: tiled transpose (B,L,D) -> (B,D,L) for q and k.
// 64x64 tiles, float4 global loads AND stores (256B contiguity both sides).
// ---------------------------------------------------------------------------
__global__ __launch_bounds__(256) void kA(const float* __restrict__ q,
                                          const float* __restrict__ k,
                                          float* __restrict__ qT,
                                          float* __restrict__ kT) {
  __shared__ float tq[64][65];
  __shared__ float tk[64][65];
  const int l0 = blockIdx.x * 64, d0 = blockIdx.y * 64, b = blockIdx.z;
  const int tid = threadIdx.x;
  const size_t ibase = (size_t)b * L_ * D_;
#pragma unroll
  for (int u = 0; u < 4; ++u) {
    const int idx = tid + (u << 8);          // 0..1023
    const int row = idx >> 4;                // l within tile
    const int c   = (idx & 15) << 2;         // d within tile (float4)
    const float4 vq = *(const float4*)&q[ibase + (size_t)(l0 + row) * D_ + d0 + c];
    const float4 vk = *(const float4*)&k[ibase + (size_t)(l0 + row) * D_ + d0 + c];
    tq[row][c + 0] = vq.x; tq[row][c + 1] = vq.y;
    tq[row][c + 2] = vq.z; tq[row][c + 3] = vq.w;
    tk[row][c + 0] = vk.x; tk[row][c + 1] = vk.y;
    tk[row][c + 2] = vk.z; tk[row][c + 3] = vk.w;
  }
  __syncthreads();
  const size_t obase = (size_t)b * D_ * L_;
#pragma unroll
  for (int u = 0; u < 4; ++u) {
    const int idx  = tid + (u << 8);
    const int drow = idx >> 4;               // d within tile
    const int c    = (idx & 15) << 2;        // l within tile (float4)
    float4 oq, ok;
    oq.x = tq[c + 0][drow]; oq.y = tq[c + 1][drow];
    oq.z = tq[c + 2][drow]; oq.w = tq[c + 3][drow];
    ok.x = tk[c + 0][drow]; ok.y = tk[c + 1][drow];
    ok.z = tk[c + 2][drow]; ok.w = tk[c + 3][drow];
    *(float4*)&qT[obase + (size_t)(d0 + drow) * L_ + l0 + c] = oq;
    *(float4*)&kT[obase + (size_t)(d0 + drow) * L_ + l0 + c] = ok;
  }
}

// ---------------------------------------------------------------------------
// Kernel B: 2 channels/block, 256 threads, 32 KiB LDS (A,B ping-pong).
// Forward pass-1 fused with the global load; inverse last pass fused with the
// global store. S1 spectrum in registers across the ch1 FFT. 12 barriers.
// Mixed-radix (8,8,8,4) Stockham, float2 complex LDS, XOR swizzle.
// ---------------------------------------------------------------------------
struct cf { float r, i; };
__device__ __forceinline__ cf cadd(cf a, cf b){ return {a.r+b.r, a.i+b.i}; }
__device__ __forceinline__ cf csub(cf a, cf b){ return {a.r-b.r, a.i-b.i}; }
__device__ __forceinline__ cf cmul(cf a, cf b){ return {a.r*b.r - a.i*b.i, a.r*b.i + a.i*b.r}; }
template<bool INV> __device__ __forceinline__ cf rot90(cf x){
  return INV ? cf{-x.i, x.r} : cf{x.i, -x.r};   // * +/- i
}
__device__ __forceinline__ int swz(int a){ return a ^ (((a >> 4) ^ (a >> 8)) & 15); }
__device__ __forceinline__ cf ldx(const float2* __restrict__ p, int i){
  const float2 v = p[swz(i)]; return {v.x, v.y};
}
__device__ __forceinline__ void stx(float2* __restrict__ p, int i, cf v){
  p[swz(i)] = {v.r, v.i};
}

template<bool INV>
__device__ __forceinline__ void dft8(cf a[8], cf b[8]) {
  const float H = 0.70710678118654752440f;
  cf t0 = cadd(a[0],a[4]), t1 = cadd(a[1],a[5]), t2 = cadd(a[2],a[6]), t3 = cadd(a[3],a[7]);
  cf u0 = csub(a[0],a[4]), u1 = csub(a[1],a[5]), u2 = csub(a[2],a[6]), u3 = csub(a[3],a[7]);
  const cf w1 = INV ? cf{H,  H} : cf{ H, -H};
  const cf w3 = INV ? cf{-H, H} : cf{-H, -H};
  u1 = cmul(u1, w1);
  u2 = rot90<INV>(u2);
  u3 = cmul(u3, w3);
  { cf s0 = cadd(t0,t2), s1 = csub(t0,t2), s2 = cadd(t1,t3), s3 = rot90<INV>(csub(t1,t3));
    b[0]=cadd(s0,s2); b[4]=csub(s0,s2); b[2]=cadd(s1,s3); b[6]=csub(s1,s3); }
  { cf s0 = cadd(u0,u2), s1 = csub(u0,u2), s2 = cadd(u1,u3), s3 = rot90<INV>(csub(u1,u3));
    b[1]=cadd(s0,s2); b[5]=csub(s0,s2); b[3]=cadd(s1,s3); b[7]=csub(s1,s3); }
}

// Apply twiddles w^1..w^7 (log-depth chain) and store (Stockham scatter).
template<int LOG2S>
__device__ __forceinline__ void twiddle_store(cf b[8], float2* __restrict__ dst,
                                              int j, int p, float sgn_ang) {
  float sn, cs;
  __sincosf(sgn_ang * (float)(p << LOG2S), &sn, &cs);
  const cf w1{cs, sn};
  const cf w2 = cmul(w1, w1);
  const cf w3 = cmul(w2, w1);
  const cf w4 = cmul(w2, w2);
  const cf w5 = cmul(w3, w2);
  const cf w6 = cmul(w3, w3);
  const cf w7 = cmul(w4, w3);
  b[1] = cmul(b[1], w1); b[2] = cmul(b[2], w2); b[3] = cmul(b[3], w3);
  b[4] = cmul(b[4], w4); b[5] = cmul(b[5], w5); b[6] = cmul(b[6], w6);
  b[7] = cmul(b[7], w7);
  const int wb = j + 7 * (p << LOG2S);
#pragma unroll
  for (int k = 0; k < 8; ++k) stx(dst, wb + (k << LOG2S), b[k]);
}

#define ANG_ (-0.0030679615757712823f)   // -2*pi/2048

// Forward pass 1 fused with global load: z[l] = q[l] + i*k[l].
__device__ __forceinline__ void pass8_first(const float* __restrict__ qg,
                                            const float* __restrict__ kg,
                                            float2* __restrict__ dst, int j) {
  cf a[8], b[8];
#pragma unroll
  for (int l = 0; l < 8; ++l) {
    const int ix = j + (l << 8);
    a[l] = {qg[ix], kg[ix]};
  }
  dft8<false>(a, b);
  twiddle_store<0>(b, dst, j, j, ANG_);
}

template<int LOG2S, bool INV>
__device__ __forceinline__ void pass8f2(const float2* __restrict__ src,
                                        float2* __restrict__ dst, int j) {
  const int p = j >> LOG2S;
  cf a[8], b[8];
#pragma unroll
  for (int l = 0; l < 8; ++l) a[l] = ldx(src, j + (l << 8));
  dft8<INV>(a, b);
  twiddle_store<LOG2S>(b, dst, j, p, INV ? -ANG_ : ANG_);
}

// Forward final radix-4 (s=512, twiddle-free), LDS->LDS.
__device__ __forceinline__ void pass4_fwd(const float2* __restrict__ src,
                                          float2* __restrict__ dst, int j) {
#pragma unroll
  for (int h = 0; h < 2; ++h) {
    const int jj = j + (h << 8);
    cf a0 = ldx(src, jj), a1 = ldx(src, jj + 512), a2 = ldx(src, jj + 1024), a3 = ldx(src, jj + 1536);
    cf s0 = cadd(a0,a2), s1 = csub(a0,a2), s2 = cadd(a1,a3), s3 = rot90<false>(csub(a1,a3));
    stx(dst, jj,        cadd(s0,s2));
    stx(dst, jj + 512,  cadd(s1,s3));
    stx(dst, jj + 1024, csub(s0,s2));
    stx(dst, jj + 1536, csub(s1,s3));
  }
}

// Inverse final radix-4 fused with the global store (Re->c0, Im->c1).
__device__ __forceinline__ void pass4_last(const float2* __restrict__ src,
                                           float* __restrict__ c0,
                                           float* __restrict__ c1, int j) {
  const float inv = 1.0f / (float)L_;
#pragma unroll
  for (int h = 0; h < 2; ++h) {
    const int jj = j + (h << 8);
    cf a0 = ldx(src, jj), a1 = ldx(src, jj + 512), a2 = ldx(src, jj + 1024), a3 = ldx(src, jj + 1536);
    cf s0 = cadd(a0,a2), s1 = csub(a0,a2), s2 = cadd(a1,a3), s3 = rot90<true>(csub(a1,a3));
    const cf o0 = cadd(s0,s2), o1 = cadd(s1,s3), o2 = csub(s0,s2), o3 = csub(s1,s3);
    c0[jj]        = o0.r * inv;  c1[jj]        = o0.i * inv;
    c0[jj + 512]  = o1.r * inv;  c1[jj + 512]  = o1.i * inv;
    c0[jj + 1024] = o2.r * inv;  c1[jj + 1024] = o2.i * inv;
    c0[jj + 1536] = o3.r * inv;  c1[jj + 1536] = o3.i * inv;
  }
}

__global__ __launch_bounds__(256) void kB(const float* __restrict__ qT,
                                          const float* __restrict__ kT,
                                          float* __restrict__ corrT) {
  __shared__ float2 A[L_];    // 16 KiB
  __shared__ float2 Bb[L_];   // 16 KiB   (32 KiB total)
  const int tid = threadIdx.x;
  const size_t row0 = (size_t)(blockIdx.x * 2) * L_;
  const size_t row1 = row0 + L_;

  // ---- channel 0 forward (global->pass1->Bb ... ends in A) ----
  pass8_first(qT + row0, kT + row0, Bb, tid); __syncthreads();
  pass8f2<3, false>(Bb, A, tid);              __syncthreads();
  pass8f2<6, false>(A, Bb, tid);              __syncthreads();
  pass4_fwd(Bb, A, tid);                      __syncthreads();

  // ---- spectrum S1 = Q0*conj(K0) into registers (f = tid + 256u) ----
  float s1r[4], s1i[4];
#pragma unroll
  for (int u = 0; u < 4; ++u) {
    const int f = tid + (u << 8);
    if (f == 0) {
      const cf z0 = ldx(A, 0), zn = ldx(A, 1024);
      s1r[u] = z0.r * z0.i;       // S1[0]    (real)
      s1i[u] = zn.r * zn.i;       // S1[1024] (real), packed here
    } else {
      const cf a = ldx(A, f), am = ldx(A, 2048 - f);
      const float qr = 0.5f * (a.r + am.r), qi = 0.5f * (a.i - am.i);
      const float kr = 0.5f * (a.i + am.i), ki = 0.5f * (am.r - a.r);
      s1r[u] = qr * kr + qi * ki;
      s1i[u] = qi * kr - qr * ki;
    }
  }
  // no barrier needed: next write (Bb) is fenced by the next __syncthreads.

  // ---- channel 1 forward (ends in A) ----
  pass8_first(qT + row1, kT + row1, Bb, tid); __syncthreads();
  pass8f2<3, false>(Bb, A, tid);              __syncthreads();
  pass8f2<6, false>(A, Bb, tid);              __syncthreads();
  pass4_fwd(Bb, A, tid);                      __syncthreads();

  // ---- combine: S2 from A on the fly; write Z = S1 + i*S2 into Bb ----
#pragma unroll
  for (int u = 0; u < 4; ++u) {
    const int f = tid + (u << 8);
    if (f == 0) {
      const cf z0 = ldx(A, 0), zn = ldx(A, 1024);
      const float s2_0 = z0.r * z0.i, s2_n = zn.r * zn.i;
      stx(Bb, 0,    {s1r[0], s2_0});
      stx(Bb, 1024, {s1i[0], s2_n});
    } else {
      const cf a = ldx(A, f), am = ldx(A, 2048 - f);
      const float qr = 0.5f * (a.r + am.r), qi = 0.5f * (a.i - am.i);
      const float kr = 0.5f * (a.i + am.i), ki = 0.5f * (am.r - a.r);
      const float s2r = qr * kr + qi * ki, s2i = qi * kr - qr * ki;
      stx(Bb, f,        {s1r[u] - s2i,  s1i[u] + s2r});
      stx(Bb, 2048 - f, {s1r[u] + s2i, -s1i[u] + s2r});
    }
  }
  __syncthreads();

  // ---- packed inverse; last pass stores straight to global ----
  pass8f2<0, true>(Bb, A, tid);               __syncthreads();
  pass8f2<3, true>(A, Bb, tid);               __syncthreads();
  pass8f2<6, true>(Bb, A, tid);               __syncthreads();
  pass4_last(A, corrT + row0, corrT + row1, tid);
}

// ---------------------------------------------------------------------------
// Kernel C: transpose corrT (B,D,L) -> corr_out (B,L,D) + per-(b,dtile) sums.
// 64x64 tiles, float4 global loads and stores.
// ---------------------------------------------------------------------------
__global__ __launch_bounds__(256) void kC(const float* __restrict__ corrT,
                                          float* __restrict__ corrOut,
                                          float* __restrict__ partial) {
  __shared__ float t[64][65];
  const int t0 = blockIdx.x * 64, d0 = blockIdx.y * 64, b = blockIdx.z;
  const int tid = threadIdx.x;
#pragma unroll
  for (int u = 0; u < 4; ++u) {
    const int idx  = tid + (u << 8);
    const int drow = idx >> 4;               // d within tile
    const int c    = (idx & 15) << 2;        // tau within tile (float4)
    const float4 v = *(const float4*)&corrT[((size_t)b * D_ + d0 + drow) * L_ + t0 + c];
    t[drow][c + 0] = v.x; t[drow][c + 1] = v.y;
    t[drow][c + 2] = v.z; t[drow][c + 3] = v.w;
  }
  __syncthreads();
#pragma unroll
  for (int u = 0; u < 4; ++u) {
    const int idx  = tid + (u << 8);
    const int trow = idx >> 4;               // tau within tile
    const int c    = (idx & 15) << 2;        // d within tile (float4)
    float4 o;
    o.x = t[c + 0][trow]; o.y = t[c + 1][trow];
    o.z = t[c + 2][trow]; o.w = t[c + 3][trow];
    *(float4*)&corrOut[((size_t)b * L_ + t0 + trow) * D_ + d0 + c] = o;
  }
  if (tid < 64) {                            // one thread per tau
    float s = 0.f;
#pragma unroll
    for (int i = 0; i < 64; ++i) s += t[i][tid];
    partial[((size_t)b * 8 + blockIdx.y) * L_ + t0 + tid] = s;
  }
}

// ---------------------------------------------------------------------------
// Kernel D0: reduce partial[128][L] -> g[L]  (32 blocks, deterministic)
// ---------------------------------------------------------------------------
__global__ __launch_bounds__(256) void kD0(const float* __restrict__ partial,
                                           float* __restrict__ g) {
  __shared__ float red[4][64];
  const int tl = threadIdx.x & 63, rg = threadIdx.x >> 6;
  const int tau = blockIdx.x * 64 + tl;
  float s = 0.f;
  for (int i = rg; i < 128; i += 4) s += partial[(size_t)i * L_ + tau];
  red[rg][tl] = s;
  __syncthreads();
  if (rg == 0) g[tau] = red[0][tl] + red[1][tl] + red[2][tl] + red[3][tl];
}

// ---------------------------------------------------------------------------
// Kernel D1: top-7 on g[L]; per-b softmax weights. Single small block.
// ---------------------------------------------------------------------------
__global__ __launch_bounds__(256) void kD1(const float* __restrict__ gin,
                                           const float* __restrict__ partial,
                                           int* __restrict__ oidx,
                                           float* __restrict__ ow) {
  __shared__ float g[L_];
  __shared__ float rv[256];
  __shared__ int   ri[256];
  __shared__ int   sidx[K_];
  const int tid = threadIdx.x;
#pragma unroll
  for (int u = 0; u < 8; ++u) g[tid + u * 256] = gin[tid + u * 256];
  __syncthreads();

  for (int it = 0; it < K_; ++it) {
    float bv = -1e30f; int bix = 1 << 30;
#pragma unroll
    for (int u = 0; u < 8; ++u) {
      const int tau = tid + u * 256;
      const float vv = g[tau];
      if (vv > bv || (vv == bv && tau < bix)) { bv = vv; bix = tau; }
    }
    rv[tid] = bv; ri[tid] = bix;
    __syncthreads();
    for (int off = 128; off > 0; off >>= 1) {
      if (tid < off) {
        const float v2 = rv[tid + off]; const int i2 = ri[tid + off];
        if (v2 > rv[tid] || (v2 == rv[tid] && i2 < ri[tid])) {
          rv[tid] = v2; ri[tid] = i2;
        }
      }
      __syncthreads();
    }
    if (tid == 0) { sidx[it] = ri[0]; g[ri[0]] = -3e38f; }
    __syncthreads();
  }

  if (tid < B_) {
    const int b = tid;
    float m[K_]; float mx = -1e30f;
    for (int kk = 0; kk < K_; ++kk) {
      float s = 0.f;
      for (int dt = 0; dt < 8; ++dt)
        s += partial[((size_t)b * 8 + dt) * L_ + sidx[kk]];
      m[kk] = s * (1.0f / 512.0f);
      mx = fmaxf(mx, m[kk]);
    }
    float sum = 0.f;
    for (int kk = 0; kk < K_; ++kk) { m[kk] = expf(m[kk] - mx); sum += m[kk]; }
    const float inv = 1.0f / sum;
    for (int kk = 0; kk < K_; ++kk) ow[b * K_ + kk] = m[kk] * inv;
  }
  if (tid < K_) oidx[tid] = sidx[tid];
}

// ---------------------------------------------------------------------------
// Kernel E: out[b,l,:] = sum_k w[b,k] * v[b, (l+idx[k])%L, :]   (float4)
// ---------------------------------------------------------------------------
__global__ __launch_bounds__(256) void kE(const float4* __restrict__ v4,
                                          const float* __restrict__ w,
                                          const int* __restrict__ idx,
                                          float4* __restrict__ out4) {
  const int bx = blockIdx.x;
  const int b  = bx >> 10;
  const int l  = ((bx & 1023) << 1) | (threadIdx.x >> 7);
  const int j  = threadIdx.x & 127;

  float ww[K_]; int rr[K_];
#pragma unroll
  for (int kk = 0; kk < K_; ++kk) {
    ww[kk] = w[b * K_ + kk];
    int r = l + idx[kk];
    if (r >= L_) r -= L_;
    rr[kk] = r;
  }
  const size_t vb = (size_t)b * L_ * 128;
  float4 acc = make_float4(0.f, 0.f, 0.f, 0.f);
#pragma unroll
  for (int kk = 0; kk < K_; ++kk) {
    const float4 vv = v4[vb + (size_t)rr[kk] * 128 + j];
    acc.x += ww[kk] * vv.x; acc.y += ww[kk] * vv.y;
    acc.z += ww[kk] * vv.z; acc.w += ww[kk] * vv.w;
  }
  out4[vb + (size_t)l * 128 + j] = acc;
}

// ---------------------------------------------------------------------------
extern "C" void kernel_launch(void* const* d_in, const int* in_sizes, int n_in,
                              void* d_out, int out_size, void* d_ws, size_t ws_size,
                              hipStream_t stream) {
  const float* q = (const float*)d_in[0];
  const float* k = (const float*)d_in[1];
  const float* v = (const float*)d_in[2];

  float* out     = (float*)d_out;        // final out  [0, Q_)
  float* corrOut = out + Q_;             // final corr [Q_, 2Q_)
  float* qT = out;                       // scratch: dead before kE overwrites
  float* kT = corrOut;                   // scratch: dead before kC overwrites

  float* corrT   = (float*)d_ws;                 // Q_ floats
  float* partial = corrT + Q_;                   // 16*8*2048 = 262144 floats
  int*   oidx    = (int*)(partial + (size_t)B_ * 8 * L_);
  float* ow      = (float*)(oidx + 16);
  float* g2048   = corrT;                        // corrT dead after kC

  kA<<<dim3(L_ / 64, D_ / 64, B_), 256, 0, stream>>>(q, k, qT, kT);
  kB<<<(B_ * D_) / 2, 256, 0, stream>>>(qT, kT, corrT);
  kC<<<dim3(L_ / 64, D_ / 64, B_), 256, 0, stream>>>(corrT, corrOut, partial);
  kD0<<<32, 256, 0, stream>>>(partial, g2048);
  kD1<<<1, 256, 0, stream>>>(g2048, partial, oidx, ow);
  kE<<<(B_ * L_) / 2, 256, 0, stream>>>((const float4*)v, ow, oidx, (float4*)out);
}

// Round 8
// 187.153 us; speedup vs baseline: 1.7998x; 1.0784x over previous
//
#include <hip/hip_runtime.h>
#include <math.h>

#define B_  16
#define L_  2048
#define D_  512
#define K_  7
#define Q_  (B_*L_*D_)   // 16777216 elements per output tensor

// bf16 helpers (RNE pack, shift unpack)
__device__ __forceinline__ ushort f2bf(float x){
  uint u = __float_as_uint(x);
  u += 0x7FFFu + ((u >> 16) & 1u);
  return (ushort)(u >> 16);
}
__device__ __forceinline__ float bf2f(ushort h){
  return __uint_as_float((uint)h << 16);
}

// ---------------------------------------------------------------------------
// Kernel A: tiled transpose (B,L,D) f32 -> (B,D,L) bf16 for q and k.
// One tensor per block (z = tensor*16 + b) -> 16.9 KiB LDS, high concurrency.
// ---------------------------------------------------------------------------
__global__ __launch_bounds__(256) void kA(const float* __restrict__ q,
                                          const float* __restrict__ k,
                                          ushort* __restrict__ qT,
                                          ushort* __restrict__ kT) {
  __shared__ float t[64][65];
  const int l0 = blockIdx.x * 64, d0 = blockIdx.y * 64;
  const int b = blockIdx.z & 15, ten = blockIdx.z >> 4;
  const float*  __restrict__ src = ten ? k : q;
  ushort* __restrict__ dst = ten ? kT : qT;
  const int tid = threadIdx.x;
  const size_t ibase = (size_t)b * L_ * D_;
#pragma unroll
  for (int u = 0; u < 4; ++u) {
    const int idx = tid + (u << 8);          // 0..1023
    const int row = idx >> 4;                // l within tile
    const int c   = (idx & 15) << 2;         // d within tile (float4)
    const float4 v = *(const float4*)&src[ibase + (size_t)(l0 + row) * D_ + d0 + c];
    t[row][c + 0] = v.x; t[row][c + 1] = v.y;
    t[row][c + 2] = v.z; t[row][c + 3] = v.w;
  }
  __syncthreads();
  const size_t obase = (size_t)b * D_ * L_;
#pragma unroll
  for (int u = 0; u < 4; ++u) {
    const int idx  = tid + (u << 8);
    const int drow = idx >> 4;               // d within tile
    const int c    = (idx & 15) << 2;        // l within tile (ushort4)
    ushort4 o;
    o.x = f2bf(t[c + 0][drow]); o.y = f2bf(t[c + 1][drow]);
    o.z = f2bf(t[c + 2][drow]); o.w = f2bf(t[c + 3][drow]);
    *(ushort4*)&dst[obase + (size_t)(d0 + drow) * L_ + l0 + c] = o;
  }
}

// ---------------------------------------------------------------------------
// Kernel B: 2 channels/block, 256 threads, 32 KiB LDS (A,B ping-pong).
// bf16 global in/out; f32 compute. Forward pass-1 fused with global load;
// inverse last pass fused with global store. S1 spectrum in registers.
// Mixed-radix (8,8,8,4) Stockham, float2 complex LDS, XOR swizzle.
// ---------------------------------------------------------------------------
struct cf { float r, i; };
__device__ __forceinline__ cf cadd(cf a, cf b){ return {a.r+b.r, a.i+b.i}; }
__device__ __forceinline__ cf csub(cf a, cf b){ return {a.r-b.r, a.i-b.i}; }
__device__ __forceinline__ cf cmul(cf a, cf b){ return {a.r*b.r - a.i*b.i, a.r*b.i + a.i*b.r}; }
template<bool INV> __device__ __forceinline__ cf rot90(cf x){
  return INV ? cf{-x.i, x.r} : cf{x.i, -x.r};   // * +/- i
}
__device__ __forceinline__ int swz(int a){ return a ^ (((a >> 4) ^ (a >> 8)) & 15); }
__device__ __forceinline__ cf ldx(const float2* __restrict__ p, int i){
  const float2 v = p[swz(i)]; return {v.x, v.y};
}
__device__ __forceinline__ void stx(float2* __restrict__ p, int i, cf v){
  p[swz(i)] = {v.r, v.i};
}

template<bool INV>
__device__ __forceinline__ void dft8(cf a[8], cf b[8]) {
  const float H = 0.70710678118654752440f;
  cf t0 = cadd(a[0],a[4]), t1 = cadd(a[1],a[5]), t2 = cadd(a[2],a[6]), t3 = cadd(a[3],a[7]);
  cf u0 = csub(a[0],a[4]), u1 = csub(a[1],a[5]), u2 = csub(a[2],a[6]), u3 = csub(a[3],a[7]);
  const cf w1 = INV ? cf{H,  H} : cf{ H, -H};
  const cf w3 = INV ? cf{-H, H} : cf{-H, -H};
  u1 = cmul(u1, w1);
  u2 = rot90<INV>(u2);
  u3 = cmul(u3, w3);
  { cf s0 = cadd(t0,t2), s1 = csub(t0,t2), s2 = cadd(t1,t3), s3 = rot90<INV>(csub(t1,t3));
    b[0]=cadd(s0,s2); b[4]=csub(s0,s2); b[2]=cadd(s1,s3); b[6]=csub(s1,s3); }
  { cf s0 = cadd(u0,u2), s1 = csub(u0,u2), s2 = cadd(u1,u3), s3 = rot90<INV>(csub(u1,u3));
    b[1]=cadd(s0,s2); b[5]=csub(s0,s2); b[3]=cadd(s1,s3); b[7]=csub(s1,s3); }
}

// Apply twiddles w^1..w^7 (log-depth chain) and store (Stockham scatter).
template<int LOG2S>
__device__ __forceinline__ void twiddle_store(cf b[8], float2* __restrict__ dst,
                                              int j, int p, float sgn_ang) {
  float sn, cs;
  __sincosf(sgn_ang * (float)(p << LOG2S), &sn, &cs);
  const cf w1{cs, sn};
  const cf w2 = cmul(w1, w1);
  const cf w3 = cmul(w2, w1);
  const cf w4 = cmul(w2, w2);
  const cf w5 = cmul(w3, w2);
  const cf w6 = cmul(w3, w3);
  const cf w7 = cmul(w4, w3);
  b[1] = cmul(b[1], w1); b[2] = cmul(b[2], w2); b[3] = cmul(b[3], w3);
  b[4] = cmul(b[4], w4); b[5] = cmul(b[5], w5); b[6] = cmul(b[6], w6);
  b[7] = cmul(b[7], w7);
  const int wb = j + 7 * (p << LOG2S);
#pragma unroll
  for (int k = 0; k < 8; ++k) stx(dst, wb + (k << LOG2S), b[k]);
}

#define ANG_ (-0.0030679615757712823f)   // -2*pi/2048

// Forward pass 1 fused with bf16 global load: z[l] = q[l] + i*k[l].
__device__ __forceinline__ void pass8_first(const ushort* __restrict__ qg,
                                            const ushort* __restrict__ kg,
                                            float2* __restrict__ dst, int j) {
  cf a[8], b[8];
#pragma unroll
  for (int l = 0; l < 8; ++l) {
    const int ix = j + (l << 8);
    a[l] = {bf2f(qg[ix]), bf2f(kg[ix])};
  }
  dft8<false>(a, b);
  twiddle_store<0>(b, dst, j, j, ANG_);
}

template<int LOG2S, bool INV>
__device__ __forceinline__ void pass8f2(const float2* __restrict__ src,
                                        float2* __restrict__ dst, int j) {
  const int p = j >> LOG2S;
  cf a[8], b[8];
#pragma unroll
  for (int l = 0; l < 8; ++l) a[l] = ldx(src, j + (l << 8));
  dft8<INV>(a, b);
  twiddle_store<LOG2S>(b, dst, j, p, INV ? -ANG_ : ANG_);
}

// Forward final radix-4 (s=512, twiddle-free), LDS->LDS.
__device__ __forceinline__ void pass4_fwd(const float2* __restrict__ src,
                                          float2* __restrict__ dst, int j) {
#pragma unroll
  for (int h = 0; h < 2; ++h) {
    const int jj = j + (h << 8);
    cf a0 = ldx(src, jj), a1 = ldx(src, jj + 512), a2 = ldx(src, jj + 1024), a3 = ldx(src, jj + 1536);
    cf s0 = cadd(a0,a2), s1 = csub(a0,a2), s2 = cadd(a1,a3), s3 = rot90<false>(csub(a1,a3));
    stx(dst, jj,        cadd(s0,s2));
    stx(dst, jj + 512,  cadd(s1,s3));
    stx(dst, jj + 1024, csub(s0,s2));
    stx(dst, jj + 1536, csub(s1,s3));
  }
}

// Inverse final radix-4 fused with the bf16 global store (Re->c0, Im->c1).
__device__ __forceinline__ void pass4_last(const float2* __restrict__ src,
                                           ushort* __restrict__ c0,
                                           ushort* __restrict__ c1, int j) {
  const float inv = 1.0f / (float)L_;
#pragma unroll
  for (int h = 0; h < 2; ++h) {
    const int jj = j + (h << 8);
    cf a0 = ldx(src, jj), a1 = ldx(src, jj + 512), a2 = ldx(src, jj + 1024), a3 = ldx(src, jj + 1536);
    cf s0 = cadd(a0,a2), s1 = csub(a0,a2), s2 = cadd(a1,a3), s3 = rot90<true>(csub(a1,a3));
    const cf o0 = cadd(s0,s2), o1 = cadd(s1,s3), o2 = csub(s0,s2), o3 = csub(s1,s3);
    c0[jj]        = f2bf(o0.r * inv);  c1[jj]        = f2bf(o0.i * inv);
    c0[jj + 512]  = f2bf(o1.r * inv);  c1[jj + 512]  = f2bf(o1.i * inv);
    c0[jj + 1024] = f2bf(o2.r * inv);  c1[jj + 1024] = f2bf(o2.i * inv);
    c0[jj + 1536] = f2bf(o3.r * inv);  c1[jj + 1536] = f2bf(o3.i * inv);
  }
}

__global__ __launch_bounds__(256) void kB(const ushort* __restrict__ qT,
                                          const ushort* __restrict__ kT,
                                          ushort* __restrict__ corrT) {
  __shared__ float2 A[L_];    // 16 KiB
  __shared__ float2 Bb[L_];   // 16 KiB   (32 KiB total)
  const int tid = threadIdx.x;
  const size_t row0 = (size_t)(blockIdx.x * 2) * L_;
  const size_t row1 = row0 + L_;

  // ---- channel 0 forward (global->pass1->Bb ... ends in A) ----
  pass8_first(qT + row0, kT + row0, Bb, tid); __syncthreads();
  pass8f2<3, false>(Bb, A, tid);              __syncthreads();
  pass8f2<6, false>(A, Bb, tid);              __syncthreads();
  pass4_fwd(Bb, A, tid);                      __syncthreads();

  // ---- spectrum S1 = Q0*conj(K0) into registers (f = tid + 256u) ----
  float s1r[4], s1i[4];
#pragma unroll
  for (int u = 0; u < 4; ++u) {
    const int f = tid + (u << 8);
    if (f == 0) {
      const cf z0 = ldx(A, 0), zn = ldx(A, 1024);
      s1r[u] = z0.r * z0.i;       // S1[0]    (real)
      s1i[u] = zn.r * zn.i;       // S1[1024] (real), packed here
    } else {
      const cf a = ldx(A, f), am = ldx(A, 2048 - f);
      const float qr = 0.5f * (a.r + am.r), qi = 0.5f * (a.i - am.i);
      const float kr = 0.5f * (a.i + am.i), ki = 0.5f * (am.r - a.r);
      s1r[u] = qr * kr + qi * ki;
      s1i[u] = qi * kr - qr * ki;
    }
  }
  // no barrier needed: next write (Bb) is fenced by the next __syncthreads.

  // ---- channel 1 forward (ends in A) ----
  pass8_first(qT + row1, kT + row1, Bb, tid); __syncthreads();
  pass8f2<3, false>(Bb, A, tid);              __syncthreads();
  pass8f2<6, false>(A, Bb, tid);              __syncthreads();
  pass4_fwd(Bb, A, tid);                      __syncthreads();

  // ---- combine: S2 from A on the fly; write Z = S1 + i*S2 into Bb ----
#pragma unroll
  for (int u = 0; u < 4; ++u) {
    const int f = tid + (u << 8);
    if (f == 0) {
      const cf z0 = ldx(A, 0), zn = ldx(A, 1024);
      const float s2_0 = z0.r * z0.i, s2_n = zn.r * zn.i;
      stx(Bb, 0,    {s1r[0], s2_0});
      stx(Bb, 1024, {s1i[0], s2_n});
    } else {
      const cf a = ldx(A, f), am = ldx(A, 2048 - f);
      const float qr = 0.5f * (a.r + am.r), qi = 0.5f * (a.i - am.i);
      const float kr = 0.5f * (a.i + am.i), ki = 0.5f * (am.r - a.r);
      const float s2r = qr * kr + qi * ki, s2i = qi * kr - qr * ki;
      stx(Bb, f,        {s1r[u] - s2i,  s1i[u] + s2r});
      stx(Bb, 2048 - f, {s1r[u] + s2i, -s1i[u] + s2r});
    }
  }
  __syncthreads();

  // ---- packed inverse; last pass stores straight to global (bf16) ----
  pass8f2<0, true>(Bb, A, tid);               __syncthreads();
  pass8f2<3, true>(A, Bb, tid);               __syncthreads();
  pass8f2<6, true>(Bb, A, tid);               __syncthreads();
  pass4_last(A, corrT + row0, corrT + row1, tid);
}

// ---------------------------------------------------------------------------
// Kernel C: transpose corrT bf16 (B,D,L) -> corr_out f32 (B,L,D)
// + per-(b,dtile) sums. 64x64 tiles.
// ---------------------------------------------------------------------------
__global__ __launch_bounds__(256) void kC(const ushort* __restrict__ corrT,
                                          float* __restrict__ corrOut,
                                          float* __restrict__ partial) {
  __shared__ float t[64][65];
  const int t0 = blockIdx.x * 64, d0 = blockIdx.y * 64, b = blockIdx.z;
  const int tid = threadIdx.x;
#pragma unroll
  for (int u = 0; u < 4; ++u) {
    const int idx  = tid + (u << 8);
    const int drow = idx >> 4;               // d within tile
    const int c    = (idx & 15) << 2;        // tau within tile (ushort4)
    const ushort4 v = *(const ushort4*)&corrT[((size_t)b * D_ + d0 + drow) * L_ + t0 + c];
    t[drow][c + 0] = bf2f(v.x); t[drow][c + 1] = bf2f(v.y);
    t[drow][c + 2] = bf2f(v.z); t[drow][c + 3] = bf2f(v.w);
  }
  __syncthreads();
#pragma unroll
  for (int u = 0; u < 4; ++u) {
    const int idx  = tid + (u << 8);
    const int trow = idx >> 4;               // tau within tile
    const int c    = (idx & 15) << 2;        // d within tile (float4)
    float4 o;
    o.x = t[c + 0][trow]; o.y = t[c + 1][trow];
    o.z = t[c + 2][trow]; o.w = t[c + 3][trow];
    *(float4*)&corrOut[((size_t)b * L_ + t0 + trow) * D_ + d0 + c] = o;
  }
  if (tid < 64) {                            // one thread per tau
    float s = 0.f;
#pragma unroll
    for (int i = 0; i < 64; ++i) s += t[i][tid];
    partial[((size_t)b * 8 + blockIdx.y) * L_ + t0 + tid] = s;
  }
}

// ---------------------------------------------------------------------------
// Kernel D0: reduce partial[128][L] -> g[L]  (32 blocks, deterministic)
// ---------------------------------------------------------------------------
__global__ __launch_bounds__(256) void kD0(const float* __restrict__ partial,
                                           float* __restrict__ g) {
  __shared__ float red[4][64];
  const int tl = threadIdx.x & 63, rg = threadIdx.x >> 6;
  const int tau = blockIdx.x * 64 + tl;
  float s = 0.f;
  for (int i = rg; i < 128; i += 4) s += partial[(size_t)i * L_ + tau];
  red[rg][tl] = s;
  __syncthreads();
  if (rg == 0) g[tau] = red[0][tl] + red[1][tl] + red[2][tl] + red[3][tl];
}

// ---------------------------------------------------------------------------
// Kernel D1: top-7 on g[L]; per-b softmax weights. Single small block.
// ---------------------------------------------------------------------------
__global__ __launch_bounds__(256) void kD1(const float* __restrict__ gin,
                                           const float* __restrict__ partial,
                                           int* __restrict__ oidx,
                                           float* __restrict__ ow) {
  __shared__ float g[L_];
  __shared__ float rv[256];
  __shared__ int   ri[256];
  __shared__ int   sidx[K_];
  const int tid = threadIdx.x;
#pragma unroll
  for (int u = 0; u < 8; ++u) g[tid + u * 256] = gin[tid + u * 256];
  __syncthreads();

  for (int it = 0; it < K_; ++it) {
    float bv = -1e30f; int bix = 1 << 30;
#pragma unroll
    for (int u = 0; u < 8; ++u) {
      const int tau = tid + u * 256;
      const float vv = g[tau];
      if (vv > bv || (vv == bv && tau < bix)) { bv = vv; bix = tau; }
    }
    rv[tid] = bv; ri[tid] = bix;
    __syncthreads();
    for (int off = 128; off > 0; off >>= 1) {
      if (tid < off) {
        const float v2 = rv[tid + off]; const int i2 = ri[tid + off];
        if (v2 > rv[tid] || (v2 == rv[tid] && i2 < ri[tid])) {
          rv[tid] = v2; ri[tid] = i2;
        }
      }
      __syncthreads();
    }
    if (tid == 0) { sidx[it] = ri[0]; g[ri[0]] = -3e38f; }
    __syncthreads();
  }

  if (tid < B_) {
    const int b = tid;
    float m[K_]; float mx = -1e30f;
    for (int kk = 0; kk < K_; ++kk) {
      float s = 0.f;
      for (int dt = 0; dt < 8; ++dt)
        s += partial[((size_t)b * 8 + dt) * L_ + sidx[kk]];
      m[kk] = s * (1.0f / 512.0f);
      mx = fmaxf(mx, m[kk]);
    }
    float sum = 0.f;
    for (int kk = 0; kk < K_; ++kk) { m[kk] = expf(m[kk] - mx); sum += m[kk]; }
    const float inv = 1.0f / sum;
    for (int kk = 0; kk < K_; ++kk) ow[b * K_ + kk] = m[kk] * inv;
  }
  if (tid < K_) oidx[tid] = sidx[tid];
}

// ---------------------------------------------------------------------------
// Kernel E: out[b,l,:] = sum_k w[b,k] * v[b, (l+idx[k])%L, :]   (float4)
// ---------------------------------------------------------------------------
__global__ __launch_bounds__(256) void kE(const float4* __restrict__ v4,
                                          const float* __restrict__ w,
                                          const int* __restrict__ idx,
                                          float4* __restrict__ out4) {
  const int bx = blockIdx.x;
  const int b  = bx >> 10;
  const int l  = ((bx & 1023) << 1) | (threadIdx.x >> 7);
  const int j  = threadIdx.x & 127;

  float ww[K_]; int rr[K_];
#pragma unroll
  for (int kk = 0; kk < K_; ++kk) {
    ww[kk] = w[b * K_ + kk];
    int r = l + idx[kk];
    if (r >= L_) r -= L_;
    rr[kk] = r;
  }
  const size_t vb = (size_t)b * L_ * 128;
  float4 acc = make_float4(0.f, 0.f, 0.f, 0.f);
#pragma unroll
  for (int kk = 0; kk < K_; ++kk) {
    const float4 vv = v4[vb + (size_t)rr[kk] * 128 + j];
    acc.x += ww[kk] * vv.x; acc.y += ww[kk] * vv.y;
    acc.z += ww[kk] * vv.z; acc.w += ww[kk] * vv.w;
  }
  out4[vb + (size_t)l * 128 + j] = acc;
}

// ---------------------------------------------------------------------------
extern "C" void kernel_launch(void* const* d_in, const int* in_sizes, int n_in,
                              void* d_out, int out_size, void* d_ws, size_t ws_size,
                              hipStream_t stream) {
  const float* q = (const float*)d_in[0];
  const float* k = (const float*)d_in[1];
  const float* v = (const float*)d_in[2];

  float* out     = (float*)d_out;        // final out  [0, Q_)
  float* corrOut = out + Q_;             // final corr [Q_, 2Q_)
  // bf16 transpose scratch inside d_out (regions dead before overwrite):
  ushort* qT16 = (ushort*)out;           // consumed by kB before kE overwrites
  ushort* kT16 = (ushort*)corrOut;       // consumed by kB before kC overwrites

  ushort* corrT16 = (ushort*)d_ws;                       // Q_ ushorts (32 MB)
  float*  partial = (float*)(corrT16 + Q_);              // 16*8*2048 floats
  float*  g2048   = partial + (size_t)B_ * 8 * L_;       // 2048 floats
  int*    oidx    = (int*)(g2048 + L_);                  // 16 ints
  float*  ow      = (float*)(oidx + 16);                 // 112 floats

  kA<<<dim3(L_ / 64, D_ / 64, B_ * 2), 256, 0, stream>>>(q, k, qT16, kT16);
  kB<<<(B_ * D_) / 2, 256, 0, stream>>>(qT16, kT16, corrT16);
  kC<<<dim3(L_ / 64, D_ / 64, B_), 256, 0, stream>>>(corrT16, corrOut, partial);
  kD0<<<32, 256, 0, stream>>>(partial, g2048);
  kD1<<<1, 256, 0, stream>>>(g2048, partial, oidx, ow);
  kE<<<(B_ * L_) / 2, 256, 0, stream>>>((const float4*)v, ow, oidx, (float4*)out);
}